// Round 1
// baseline (121.573 us; speedup 1.0000x reference)
//
#include <hip/hip_runtime.h>
#include <math.h>

#define BB 8
#define SS 4096
#define DD 1024
#define HH 16

// ws layout:
//   logits/weights [BB][SS][HH] fp32  = 2 MB   (offset 0)
//   partial [32][BB][HH][DD] fp32     = 16 MB  (offset 2 MB)
// total 18 MB required in d_ws.

__device__ __forceinline__ float wave_max64(float v) {
#pragma unroll
  for (int off = 32; off > 0; off >>= 1) v = fmaxf(v, __shfl_xor(v, off, 64));
  return v;
}
__device__ __forceinline__ float wave_sum64(float v) {
#pragma unroll
  for (int off = 32; off > 0; off >>= 1) v += __shfl_xor(v, off, 64);
  return v;
}

// K1: logits[b][s][h] = mask ? dot(x[b,s,:], W[:,h]) * 0.125 : -inf
// grid 512 (= 8 b * 64 s-tiles of 64 rows), block 256 (4 waves).
// lane = s-row within tile; wave w owns d-quarter [w*256, w*256+256).
__global__ __launch_bounds__(256) void k_logits(
    const float* __restrict__ x, const float* __restrict__ W,
    const int* __restrict__ mask, float* __restrict__ logits) {
  __shared__ float xt[64][129];    // +1 pad: column reads conflict-free
  __shared__ float red[4][64][17]; // +1 pad for reduce writes

  const int tid = threadIdx.x;
  const int lane = tid & 63;
  const int wv = __builtin_amdgcn_readfirstlane(tid >> 6); // force SGPR
  const int b = blockIdx.x >> 6;
  const int s0 = (blockIdx.x & 63) * 64;
  const float* xb = x + ((size_t)b * SS + s0) * DD;

  float acc[HH];
#pragma unroll
  for (int h = 0; h < HH; ++h) acc[h] = 0.f;

  for (int c = 0; c < 8; ++c) {
    // stage x[64 rows][128 cols] of this d-chunk, coalesced (512B per 32-thr group)
#pragma unroll
    for (int k = 0; k < 8; ++k) {
      int f = k * 256 + tid;
      int r = f >> 5, c4 = f & 31;
      float4 v = *reinterpret_cast<const float4*>(xb + (size_t)r * DD + c * 128 + c4 * 4);
      float* p = &xt[r][c4 * 4];   // scalar stores: LDS b128 would be misaligned w/ pad 1
      p[0] = v.x; p[1] = v.y; p[2] = v.z; p[3] = v.w;
    }
    __syncthreads();
    // wave wv consumes cols [wv*32, wv*32+32) of the chunk
#pragma unroll 4
    for (int j = 0; j < 32; ++j) {
      int dl = wv * 32 + j;
      float xv = xt[lane][dl];                       // stride 129 -> 2 lanes/bank (free)
      const float* wp = W + (c * 128 + dl) * HH;     // uniform addr -> s_load
#pragma unroll
      for (int h = 0; h < HH; ++h) acc[h] += xv * wp[h];  // v_fmac v,s,v
    }
    __syncthreads();
  }

  // cross-wave reduce (4 partials per (s,h))
#pragma unroll
  for (int h = 0; h < HH; ++h) red[wv][lane][h] = acc[h];
  __syncthreads();

  const int* mb = mask + b * SS + s0;
  float* lb = logits + ((size_t)b * SS + s0) * HH;
#pragma unroll
  for (int k = 0; k < 4; ++k) {
    int idx = k * 256 + tid;
    int sl = idx >> 4, h = idx & 15;
    float v = red[0][sl][h] + red[1][sl][h] + red[2][sl][h] + red[3][sl][h];
    v *= 0.125f;                                     // 1/sqrt(head_dim=64)
    lb[(size_t)sl * HH + h] = (mb[sl] == 0) ? -INFINITY : v;
  }
}

// K2: per (b,h) masked softmax over S=4096, normalize in place.
// grid 128 (= 8 b * 16 h), block 256; each thread holds 16 values in regs.
__global__ __launch_bounds__(256) void k_softmax(float* __restrict__ logits) {
  __shared__ float sred[4];
  const int tid = threadIdx.x;
  const int lane = tid & 63;
  const int wv = tid >> 6;
  const int b = blockIdx.x >> 4;
  const int h = blockIdx.x & 15;
  float* base = logits + (size_t)b * SS * HH + h;

  float v[16];
  float m = -INFINITY;
#pragma unroll
  for (int k = 0; k < 16; ++k) {
    v[k] = base[(size_t)(k * 256 + tid) * HH];
    m = fmaxf(m, v[k]);
  }
  m = wave_max64(m);
  if (lane == 0) sred[wv] = m;
  __syncthreads();
  m = fmaxf(fmaxf(sred[0], sred[1]), fmaxf(sred[2], sred[3]));
  __syncthreads();

  float ssum = 0.f;
#pragma unroll
  for (int k = 0; k < 16; ++k) {
    v[k] = __expf(v[k] - m);   // -inf -> 0 for masked rows
    ssum += v[k];
  }
  ssum = wave_sum64(ssum);
  if (lane == 0) sred[wv] = ssum;
  __syncthreads();
  float inv = 1.0f / (sred[0] + sred[1] + sred[2] + sred[3]);
#pragma unroll
  for (int k = 0; k < 16; ++k) base[(size_t)(k * 256 + tid) * HH] = v[k] * inv;
}

// K3: partial[b-chunk] pooling. grid 256 (= 8 b * 32 s-chunks of 128 rows),
// block 256; thread owns d = 4*tid..4*tid+3 (block covers full D=1024).
__global__ __launch_bounds__(256) void k_pool(
    const float* __restrict__ x, const float* __restrict__ wn,
    float* __restrict__ partial) {
  __shared__ float wl[128][16];  // 8 KB weight tile
  const int tid = threadIdx.x;
  const int b = blockIdx.x >> 5;
  const int sc = blockIdx.x & 31;
  const int s0 = sc * 128;

#pragma unroll
  for (int k = 0; k < 2; ++k) {
    int f = k * 256 + tid;  // float4 id, 512 total
    float4 v = *reinterpret_cast<const float4*>(wn + ((size_t)b * SS + s0) * HH + f * 4);
    *reinterpret_cast<float4*>(&wl[0][0] + f * 4) = v;
  }
  __syncthreads();

  float4 acc[HH];
#pragma unroll
  for (int h = 0; h < HH; ++h) acc[h] = make_float4(0.f, 0.f, 0.f, 0.f);

  const float* xb = x + ((size_t)b * SS + s0) * DD + tid * 4;
  for (int s = 0; s < 128; ++s) {
    float4 xv = *reinterpret_cast<const float4*>(xb + (size_t)s * DD);
    // uniform-address b128 broadcasts (free), components to regs
    const float4* wrow = reinterpret_cast<const float4*>(wl[s]);
    float4 wa = wrow[0], wb_ = wrow[1], wc = wrow[2], wd = wrow[3];
    float wvv[16] = {wa.x, wa.y, wa.z, wa.w, wb_.x, wb_.y, wb_.z, wb_.w,
                     wc.x, wc.y, wc.z, wc.w, wd.x, wd.y, wd.z, wd.w};
#pragma unroll
    for (int h = 0; h < HH; ++h) {
      float w = wvv[h];
      acc[h].x += w * xv.x; acc[h].y += w * xv.y;
      acc[h].z += w * xv.z; acc[h].w += w * xv.w;
    }
  }

  float* pb = partial + ((size_t)sc * BB + b) * (HH * DD) + tid * 4;
#pragma unroll
  for (int h = 0; h < HH; ++h)
    *reinterpret_cast<float4*>(pb + (size_t)h * DD) = acc[h];
}

// K4: out[idx] = sum over 32 s-chunks of partial. grid 512, block 256.
__global__ __launch_bounds__(256) void k_reduce(
    const float* __restrict__ partial, float* __restrict__ out) {
  const int idx = blockIdx.x * 256 + threadIdx.x;
  float s = 0.f;
#pragma unroll
  for (int c = 0; c < 32; ++c) s += partial[(size_t)c * (BB * HH * DD) + idx];
  out[idx] = s;
}

extern "C" void kernel_launch(void* const* d_in, const int* in_sizes, int n_in,
                              void* d_out, int out_size, void* d_ws, size_t ws_size,
                              hipStream_t stream) {
  const float* x = (const float*)d_in[0];     // [8][4096][1024] fp32
  const float* W = (const float*)d_in[1];     // [1024][16] fp32
  const int* mask = (const int*)d_in[2];      // [8][4096] int32
  float* out = (float*)d_out;                 // [8][16384] fp32

  float* logits = (float*)d_ws;                                   // 2 MB
  float* partial = (float*)((char*)d_ws + (size_t)BB * SS * HH * 4); // 16 MB

  k_logits<<<512, 256, 0, stream>>>(x, W, mask, logits);
  k_softmax<<<128, 256, 0, stream>>>(logits);
  k_pool<<<256, 256, 0, stream>>>(x, logits, partial);
  k_reduce<<<512, 256, 0, stream>>>(partial, out);
}